// Round 1
// 378.613 us; speedup vs baseline: 1.0173x; 1.0173x over previous
//
#include <hip/hip_runtime.h>

#define BATCH 32768
#define NVEC  4096
#define EDIM  256
#define KNN   20

#define BM 64            // samples per block
#define NTHREADS 512     // 8 waves (was 4) -> 4 waves/SIMD at 2 blocks/CU
#define RPW 512          // rows scanned per wave (8 waves x 512 = all 4096)
#define NCHUNK 8         // RPW / 64
#define XPITCH 264       // x-LDS row pitch in ushorts (256+8)
#define CAP 32           // block-local candidate capacity per sample
#define MARGIN 2.0f      // > 2 * worst-case bf16 dot error (~0.7)

typedef short          s16x8 __attribute__((ext_vector_type(8)));
typedef unsigned short u16x8 __attribute__((ext_vector_type(8)));
typedef float          f32x4 __attribute__((ext_vector_type(4)));

__device__ __forceinline__ unsigned short f2bf(float f) {
  unsigned int u = __float_as_uint(f);
  u += 0x7fffu + ((u >> 16) & 1u);   // RNE; inputs finite
  return (unsigned short)(u >> 16);
}

// monotone float<->uint encoding: order-preserving over all finite floats
__device__ __forceinline__ unsigned int fenc(float f) {
  unsigned int u = __float_as_uint(f);
  return (u & 0x80000000u) ? ~u : (u | 0x80000000u);
}
__device__ __forceinline__ float fdec(unsigned int e) {
  unsigned int u = (e & 0x80000000u) ? (e ^ 0x80000000u) : ~e;
  return __uint_as_float(u);
}

// fp32 k-ascending dot — EXACT source pattern of the passing kernel
__device__ __forceinline__ float dot_np(const float4* __restrict__ xq,
                                        const float4* __restrict__ wq) {
  float d = 0.f;
  for (int k = 0; k < EDIM / 4; k++) {
    float4 a4 = xq[k], b4 = wq[k];
    d += a4.x * b4.x;
    d += a4.y * b4.y;
    d += a4.z * b4.z;
    d += a4.w * b4.w;
  }
  return d;
}

__global__ __launch_bounds__(256)
void k_convert_w(const float* __restrict__ W, unsigned short* __restrict__ Wb) {
  int i = blockIdx.x * 256 + threadIdx.x;   // 262144 float4 groups
  float4 v = ((const float4*)W)[i];
  ushort4 o; o.x = f2bf(v.x); o.y = f2bf(v.y); o.z = f2bf(v.z); o.w = f2bf(v.w);
  ((ushort4*)Wb)[i] = o;
}

// per-code weighted-window output table O[4096][256]
__global__ __launch_bounds__(256)
void k_code_out(const float* __restrict__ W, float* __restrict__ Otab) {
  const int lane = threadIdx.x & 63;
  const int code = blockIdx.x * 4 + (threadIdx.x >> 6);
  float w = 0.f;
  if (lane < 41) {
    int d = lane - KNN;
    int idx = code + d;
    bool left  = (code - KNN) < 0;
    bool valid = (idx >= 0) && (idx < NVEC) && (!left || (d < KNN));
    w = valid ? expf(-0.5f * (float)(d * d)) : 0.f;
  }
  float ssum = w;
  #pragma unroll
  for (int off = 32; off >= 1; off >>= 1) ssum += __shfl_xor(ssum, off);
  float inv = 1.f / ssum;

  float4 acc = {0.f, 0.f, 0.f, 0.f};
  #pragma unroll
  for (int d = 0; d < 41; d++) {
    float wd = __shfl(w, d);
    int idx = code + d - KNN;
    idx = idx < 0 ? 0 : (idx >= NVEC ? NVEC - 1 : idx);
    float4 wr = *(const float4*)(W + (size_t)idx * EDIM + lane * 4);
    acc.x += wd * wr.x; acc.y += wd * wr.y;
    acc.z += wd * wr.z; acc.w += wd * wr.w;
  }
  acc.x *= inv; acc.y *= inv; acc.z *= inv; acc.w *= inv;
  *(float4*)(Otab + (size_t)code * EDIM + lane * 4) = acc;
}

// fused GEMM + argmin + refine + output scatter.
// One block of 8 waves per 64 samples; wave wv owns rows wv*512..+511.
// No barriers in the row loop. a-frags double-buffered (1-deep, crossing the
// chunk tail). Shared-min exchange is read-mostly (atomic only on improve).
__global__ __launch_bounds__(NTHREADS, 4)
void k_all(const float* __restrict__ x, const float* __restrict__ W,
           const unsigned short* __restrict__ Wb,
           const float* __restrict__ Otab, float* __restrict__ out) {
  __shared__ unsigned short xs[BM * XPITCH];   // 33792 B
  __shared__ float        sval[BM * CAP];      // 8192 B
  __shared__ int          sidx[BM * CAP];      // 8192 B
  __shared__ int          scnt[BM];            // 256 B
  __shared__ unsigned int smin[BM];            // 256 B
  __shared__ int          sbad;

  const int t    = threadIdx.x;
  const int lane = t & 63;
  const int wv   = t >> 6;        // 0..7
  const int lm   = lane & 15;
  const int lq   = lane >> 4;
  const int m0   = blockIdx.x * BM;

  if (t < BM) { scnt[t] = 0; smin[t] = 0xFFFFFFFFu; }
  if (t == 0) sbad = 0;

  // ---- stage x tile: fp32 global -> RNE bf16 -> padded LDS (512 thr) ----
  {
    const int r = t >> 3, q = t & 7;           // 8 threads per row, 32 elems each
    const float* xp = x + (size_t)(m0 + r) * EDIM + q * 32;
    unsigned short* dst = xs + r * XPITCH + q * 32;
    #pragma unroll
    for (int u = 0; u < 4; u++) {
      float4 v0 = *(const float4*)(xp + u * 8);
      float4 v1 = *(const float4*)(xp + u * 8 + 4);
      u16x8 uu;
      uu[0] = f2bf(v0.x); uu[1] = f2bf(v0.y); uu[2] = f2bf(v0.z); uu[3] = f2bf(v0.w);
      uu[4] = f2bf(v1.x); uu[5] = f2bf(v1.y); uu[6] = f2bf(v1.z); uu[7] = f2bf(v1.w);
      *(u16x8*)(dst + u * 8) = uu;
    }
  }

  // preload chunk-0 s=0 W-frags (global, independent of LDS barrier)
  const unsigned short* wp = Wb + (size_t)(wv * RPW + lm) * EDIM + lq * 8;
  s16x8 a0[4], a1[4];
  #pragma unroll
  for (int i = 0; i < 4; i++)
    a0[i] = *(const s16x8*)(wp + (size_t)i * (16 * EDIM));

  __syncthreads();   // the only pre-refine barrier

  const f32x4 fz = {0.f, 0.f, 0.f, 0.f};
  float rm[4] = {3.4e38f, 3.4e38f, 3.4e38f, 3.4e38f};

  for (int nc = 0; nc < NCHUNK; nc++) {
    f32x4 acc[4][4];
    #pragma unroll
    for (int i = 0; i < 4; i++)
      #pragma unroll
      for (int j = 0; j < 4; j++) acc[i][j] = fz;

    #pragma unroll
    for (int s = 0; s < 8; s++) {
      // prefetch next s (or next chunk's s=0 at s==7: hides under the tail).
      // Last chunk's s==7 over-reads 16KB past Wb into Otab region: harmless.
      const int nxt = (s == 7) ? (64 * EDIM) : ((s + 1) * 32);
      #pragma unroll
      for (int i = 0; i < 4; i++)
        a1[i] = *(const s16x8*)(wp + (size_t)i * (16 * EDIM) + nxt);
      #pragma unroll
      for (int j = 0; j < 4; j++) {
        s16x8 bj = *(const s16x8*)(xs + (j * 16 + lm) * XPITCH + s * 32 + lq * 8);
        #pragma unroll
        for (int i = 0; i < 4; i++)
          acc[i][j] = __builtin_amdgcn_mfma_f32_16x16x32_bf16(a0[i], bj, acc[i][j], 0, 0, 0);
      }
      #pragma unroll
      for (int i = 0; i < 4; i++) a0[i] = a1[i];   // renamed away (loop unrolled)
    }

    // ---- layout self-check (chunk 0): exact dot vs acc[0][0][0] ----
    if (nc == 0) {
      float ex = dot_np((const float4*)(x + (size_t)(m0 + lm) * EDIM),
                        (const float4*)(W + (size_t)(wv * RPW + lq * 4) * EDIM));
      if (fabsf(ex - acc[0][0][0]) > 2.0f) sbad = 1;
    }

    // ---- per-sample chunk min -> running min; capture only when possible ----
    const int rb = wv * RPW + nc * 64;
    #pragma unroll
    for (int j = 0; j < 4; j++) {
      const int sl = j * 16 + lm;
      float mi0 = fminf(fminf(acc[0][j][0], acc[0][j][1]), fminf(acc[0][j][2], acc[0][j][3]));
      float mi1 = fminf(fminf(acc[1][j][0], acc[1][j][1]), fminf(acc[1][j][2], acc[1][j][3]));
      float mi2 = fminf(fminf(acc[2][j][0], acc[2][j][1]), fminf(acc[2][j][2], acc[2][j][3]));
      float mi3 = fminf(fminf(acc[3][j][0], acc[3][j][1]), fminf(acc[3][j][2], acc[3][j][3]));
      float m = fminf(fminf(mi0, mi1), fminf(mi2, mi3));
      m = fminf(m, __shfl_xor(m, 16));
      m = fminf(m, __shfl_xor(m, 32));   // all 4 lq lanes of this lm have sample min
      float rloc = fminf(rm[j], m);
      // read-mostly shared-min exchange (atomic only when this wave improves).
      // stale reads only loosen the threshold -> still correct.
      unsigned int e  = ((volatile unsigned int*)smin)[sl];
      unsigned int re = fenc(rloc);
      if (lq == 0 && re < e) atomicMin(&smin[sl], re);
      if (e < re) rloc = fdec(e);        // e==0xFFFFFFFF never taken
      rm[j] = rloc;
      const float th = rloc + MARGIN;
      if (__any(m <= th)) {              // usually false after warm-up
        #pragma unroll
        for (int i = 0; i < 4; i++)
          #pragma unroll
          for (int r = 0; r < 4; r++) {
            float v = acc[i][j][r];
            if (v <= th) {
              int row = rb + i * 16 + lq * 4 + r;
              int slot = atomicAdd(&scnt[sl], 1);
              if (slot < CAP) { sval[sl * CAP + slot] = v; sidx[sl * CAP + slot] = row; }
            }
          }
      }
    }
    wp += 64 * EDIM;
  }

  __syncthreads();   // all captures visible

  // ---- in-block refine + output scatter: np-order fp32 dots ----
  const bool bad = (sbad != 0);
  for (int u = 0; u < 8; u++) {
    const int sl = wv * 8 + u;
    const int b = m0 + sl;
    int c = scnt[sl];
    bool ovf = bad || (c > CAP);
    if (c > CAP) c = CAP;
    const float4* xq = (const float4*)(x + (size_t)b * EDIM);
    unsigned long long bestkey = 0xFFFFFFFFFFFFFFFFull;
    if (!ovf) {
      float v = 3.4e38f; int id = 0;
      if (lane < c) { v = sval[sl * CAP + lane]; id = sidx[sl * CAP + lane]; }
      float vmin = v;
      #pragma unroll
      for (int off = 32; off >= 1; off >>= 1) vmin = fminf(vmin, __shfl_xor(vmin, off));
      if (lane < c && v <= vmin + MARGIN) {
        float d = dot_np(xq, (const float4*)(W + (size_t)id * EDIM));
        bestkey = ((unsigned long long)fenc(d) << 32) | (unsigned)id;
      }
    } else {
      // fallback (layout-bad or capture overflow): full scan, np-order fp32
      for (int n = lane; n < NVEC; n += 64) {
        float d = dot_np(xq, (const float4*)(W + (size_t)n * EDIM));
        unsigned long long key = ((unsigned long long)fenc(d) << 32) | (unsigned)n;
        if (key < bestkey) bestkey = key;
      }
    }
    #pragma unroll
    for (int off = 32; off >= 1; off >>= 1) {
      unsigned long long o = __shfl_xor(bestkey, off);
      if (o < bestkey) bestkey = o;
    }
    // all lanes now hold the winning key -> gather Otab row, write out
    const int id = (int)(unsigned int)(bestkey & 0xFFFFFFFFull);
    float4 v = *(const float4*)(Otab + (size_t)id * EDIM + lane * 4);
    *(float4*)(out + (size_t)b * EDIM + lane * 4) = v;
  }
}

extern "C" void kernel_launch(void* const* d_in, const int* in_sizes, int n_in,
                              void* d_out, int out_size, void* d_ws, size_t ws_size,
                              hipStream_t stream) {
  const float* x = (const float*)d_in[0];   // [32768,256] fp32
  const float* W = (const float*)d_in[1];   // [4096,256]  fp32
  float* out = (float*)d_out;

  char* ws = (char*)d_ws;
  unsigned short* Wb = (unsigned short*)ws;                        // 2 MB
  float* Otab = (float*)(ws + (size_t)NVEC * EDIM * 2);            // 4 MB

  k_convert_w<<<NVEC * EDIM / 4 / 256, 256, 0, stream>>>(W, Wb);
  k_code_out<<<NVEC / 4, 256, 0, stream>>>(W, Otab);
  k_all<<<BATCH / BM, NTHREADS, 0, stream>>>(x, W, Wb, Otab, out);
}